// Round 9
// baseline (29.334 us; speedup 1.0000x reference)
//
#include <hip/hip_runtime.h>

// SoftTimeAttention: out[b,q,:] = sum_j softmax_j(-(T*(t_q-t_j))^2) * h[b,j,:]
// B=4, T=4096, H=256, f32. w = exp(-(4096*dt)^2) == 0 in f32 for |dt|>~2.3e-3
// => ~19 active keys/query. R4-proven structure: per-batch counting sort
// (1024 buckets), then sorted-uniform query chunks per wave with a shared
// candidate window and ballot-compacted quad-row accumulation.
// R9 delta vs R4: main uses 512-thread/8-wave blocks (256 blocks) -> 4
// waves/SIMD TLP (2x R4) to hide the shfl->L2-row-load dependent chain.

constexpr int Bb = 4;
constexpr int Tt = 4096;
constexpr int Hh = 256;
constexpr int NB = 1024;     // t-buckets per batch
// coverage: bucket distance >= 3 => |dts| > 8 scaled units... (margin 2 on
// each side as in R4; dropped terms have x > 8 => w <= e^-64 ~ 1e-28; with
// denominator >= 1 the output error is ~1e-26 per element: negligible).

// ---------------------------------------------------------------------------
// Per-batch counting sort (R4-proven, unchanged). One 1024-thr block per batch.
// Output: spair[b][pos] = { bitcast(t*4096), original_idx }, offsets[b][NB+1].
__global__ __launch_bounds__(1024) void sort_kernel(
    const float* __restrict__ tvals,
    uint2* __restrict__ spair,
    int* __restrict__ offsets)
{
    __shared__ int hist[NB];
    __shared__ int excl[NB];
    __shared__ int cnt[NB];
    __shared__ int wsum[16];
    __shared__ int wexcl[16];

    const int b    = blockIdx.x;
    const int tid  = threadIdx.x;
    const int lane = tid & 63;
    const int wv   = tid >> 6;
    const float* tb = tvals + (size_t)b * Tt;

    hist[tid] = 0;
    cnt[tid]  = 0;
    __syncthreads();

    float tv[4]; int bk[4];
    #pragma unroll
    for (int i = 0; i < 4; ++i) {
        const int j = i * 1024 + tid;
        const float t = tb[j];
        int k = (int)(t * (float)NB);
        k = k < 0 ? 0 : (k > NB - 1 ? NB - 1 : k);
        tv[i] = t * 4096.0f;      // pre-scaled for the main kernel
        bk[i] = k;
        atomicAdd(&hist[k], 1);
    }
    __syncthreads();

    // inclusive scan over 1024 buckets: wave scan + cross-wave fixup
    const int self = hist[tid];
    int x = self;
    #pragma unroll
    for (int d = 1; d < 64; d <<= 1) {
        const int y = __shfl_up(x, d);
        if (lane >= d) x += y;
    }
    if (lane == 63) wsum[wv] = x;
    __syncthreads();
    if (tid < 16) {
        int y = wsum[tid];
        #pragma unroll
        for (int d = 1; d < 16; d <<= 1) {
            const int z = __shfl_up(y, d);
            if (tid >= d) y += z;
        }
        wexcl[tid] = y - wsum[tid];
    }
    __syncthreads();
    const int incl = x + wexcl[wv];
    excl[tid] = incl - self;
    offsets[(size_t)b * (NB + 1) + tid] = incl - self;
    if (tid == 0) offsets[(size_t)b * (NB + 1) + NB] = Tt;
    __syncthreads();

    #pragma unroll
    for (int i = 0; i < 4; ++i) {
        const int k = bk[i];
        const int rank = atomicAdd(&cnt[k], 1);
        const int pos = excl[k] + rank;
        uint2 pr;
        pr.x = __float_as_uint(tv[i]);
        pr.y = (unsigned)(i * 1024 + tid);
        spair[(size_t)b * Tt + pos] = pr;
    }
}

// ---------------------------------------------------------------------------
// Main sparse kernel: 512 thr = 8 waves; each wave handles QPW=8 consecutive
// sorted queries (shared candidate window). Grid = B * T/64 = 256 blocks
// -> 16 waves/CU = 4 waves/SIMD (2x the TLP of the R4 layout).
constexpr int QPW = 8;
constexpr int MTHREADS = 512;

__global__ __launch_bounds__(MTHREADS) void stattn_sparse(
    const float* __restrict__ h_seq,
    const uint2* __restrict__ spair,
    const int* __restrict__ offsets,
    float* __restrict__ out)
{
    const int tid  = threadIdx.x;
    const int lane = tid & 63;
    const int wv   = tid >> 6;          // 0..7

    // XCD-contiguous swizzle (256 blocks = 8 XCDs x 32): 2 XCDs per batch,
    // so the 4 MB per-batch h panel stays L2-resident.
    const int phys = blockIdx.x;
    const int lb   = (phys & 7) * 32 + (phys >> 3);
    const int b    = lb >> 6;           // 64 blocks per batch
    const int blk  = lb & 63;

    const uint2* sp  = spair + (size_t)b * Tt;
    const int*   off = offsets + (size_t)b * (NB + 1);
    const float* hb  = h_seq + (size_t)b * Tt * Hh;

    const int p0 = blk * 64 + wv * QPW;     // 64 queries per block

    float tq[QPW]; int qi[QPW];
    #pragma unroll
    for (int g = 0; g < QPW; ++g) {
        const uint2 pr = sp[p0 + g];
        tq[g] = __uint_as_float(pr.x);      // t*4096
        qi[g] = (int)pr.y;
    }

    // candidate window (buckets nondecreasing along sorted positions)
    // bucket = floor(t*1024) = floor(ts * 0.25)
    int bmin = (int)(tq[0] * 0.25f);
    int bmax = (int)(tq[QPW - 1] * 0.25f);
    bmin = bmin < 0 ? 0 : (bmin > NB - 1 ? NB - 1 : bmin);
    bmax = bmax < 0 ? 0 : (bmax > NB - 1 ? NB - 1 : bmax);
    const int blo = bmin - 2 < 0 ? 0 : bmin - 2;
    const int bhi = bmax + 3 > NB ? NB : bmax + 3;
    const int lo = off[blo];
    const int hi = off[bhi];

    float4 acc[QPW];
    float  den[QPW];
    #pragma unroll
    for (int g = 0; g < QPW; ++g) {
        acc[g] = make_float4(0.f, 0.f, 0.f, 0.f);
        den[g] = 0.f;
    }

    for (int base = lo; base < hi; base += 64) {
        const int p = base + lane;
        const bool valid = p < hi;
        float tj; int jj;
        if (valid) { const uint2 pr = sp[p]; tj = __uint_as_float(pr.x); jj = (int)pr.y; }
        else       { tj = 3.0e18f; jj = 0; }   // -> w == 0 exactly

        float w[QPW]; float wmax = 0.f;
        #pragma unroll
        for (int g = 0; g < QPW; ++g) {
            const float x = tq[g] - tj;
            w[g] = __expf(-x * x);
            den[g] += w[g];
            wmax = fmaxf(wmax, w[g]);
        }

        unsigned long long mask = __ballot(wmax > 1e-20f);
        while (mask) {
            const int s0 = __builtin_ctzll(mask); mask &= mask - 1;
            const bool h1 = mask != 0;
            const int s1 = h1 ? __builtin_ctzll(mask) : s0; if (h1) mask &= mask - 1;
            const bool h2 = mask != 0;
            const int s2 = h2 ? __builtin_ctzll(mask) : s0; if (h2) mask &= mask - 1;
            const bool h3 = mask != 0;
            const int s3 = h3 ? __builtin_ctzll(mask) : s0; if (h3) mask &= mask - 1;

            const int j0 = __shfl(jj, s0);
            const int j1 = __shfl(jj, s1);
            const int j2 = __shfl(jj, s2);
            const int j3 = __shfl(jj, s3);
            float4 h0  = *(const float4*)&hb[(size_t)j0 * Hh + lane * 4];
            float4 h1v = *(const float4*)&hb[(size_t)j1 * Hh + lane * 4];
            float4 h2v = *(const float4*)&hb[(size_t)j2 * Hh + lane * 4];
            float4 h3v = *(const float4*)&hb[(size_t)j3 * Hh + lane * 4];
            if (!h1) h1v = make_float4(0.f,0.f,0.f,0.f);
            if (!h2) h2v = make_float4(0.f,0.f,0.f,0.f);
            if (!h3) h3v = make_float4(0.f,0.f,0.f,0.f);

            #pragma unroll
            for (int g = 0; g < QPW; ++g) {
                const float a0 = __shfl(w[g], s0);
                const float a1 = __shfl(w[g], s1);
                const float a2 = __shfl(w[g], s2);
                const float a3 = __shfl(w[g], s3);
                acc[g].x += a0 * h0.x + a1 * h1v.x + a2 * h2v.x + a3 * h3v.x;
                acc[g].y += a0 * h0.y + a1 * h1v.y + a2 * h2v.y + a3 * h3v.y;
                acc[g].z += a0 * h0.z + a1 * h1v.z + a2 * h2v.z + a3 * h3v.z;
                acc[g].w += a0 * h0.w + a1 * h1v.w + a2 * h2v.w + a3 * h3v.w;
            }
        }
    }

    // reduce denominators across lanes
    #pragma unroll
    for (int g = 0; g < QPW; ++g) {
        float d = den[g];
        #pragma unroll
        for (int s = 1; s < 64; s <<= 1) d += __shfl_xor(d, s);
        den[g] = d;
    }

    #pragma unroll
    for (int g = 0; g < QPW; ++g) {
        const float inv = 1.0f / den[g];
        float* orow = out + ((size_t)b * Tt + qi[g]) * Hh + lane * 4;
        float4 o;
        o.x = acc[g].x * inv; o.y = acc[g].y * inv;
        o.z = acc[g].z * inv; o.w = acc[g].w * inv;
        *(float4*)orow = o;
    }
}

// ---------------------------------------------------------------------------
// Naive dense fallback if ws is too small (never expected; kept for safety).
__global__ __launch_bounds__(64) void stattn_naive(
    const float* __restrict__ h_seq,
    const float* __restrict__ tvals,
    float* __restrict__ out)
{
    const int gid  = blockIdx.x;        // b*Tt + q
    const int b    = gid >> 12;
    const int q    = gid & (Tt - 1);
    const int lane = threadIdx.x;
    const float* tb = tvals + (size_t)b * Tt;
    const float* hb = h_seq + (size_t)b * Tt * Hh;
    const float tsq = tb[q] * 4096.0f;
    float4 acc = make_float4(0.f,0.f,0.f,0.f);
    float den = 0.f;
    for (int j = 0; j < Tt; ++j) {
        const float x = tsq - tb[j] * 4096.0f;
        const float w = __expf(-x * x);
        den += w;
        if (w > 0.f) {
            const float4 hv = *(const float4*)&hb[(size_t)j * Hh + lane * 4];
            acc.x += w * hv.x; acc.y += w * hv.y;
            acc.z += w * hv.z; acc.w += w * hv.w;
        }
    }
    const float inv = 1.0f / den;
    float4 o;
    o.x = acc.x * inv; o.y = acc.y * inv; o.z = acc.z * inv; o.w = acc.w * inv;
    *(float4*)&out[((size_t)b * Tt + q) * Hh + lane * 4] = o;
}

extern "C" void kernel_launch(void* const* d_in, const int* in_sizes, int n_in,
                              void* d_out, int out_size, void* d_ws, size_t ws_size,
                              hipStream_t stream) {
    const float* h_seq = (const float*)d_in[0];
    const float* tvals = (const float*)d_in[1];
    float* out = (float*)d_out;

    // ws layout: spair (B*T uint2) | offsets (B*(NB+1) i32)
    const size_t need = (size_t)Bb * Tt * sizeof(uint2) + (size_t)Bb * (NB + 1) * 4;
    if (ws_size >= need) {
        uint2* spair   = (uint2*)d_ws;
        int*   offsets = (int*)(spair + (size_t)Bb * Tt);
        sort_kernel<<<dim3(Bb), dim3(1024), 0, stream>>>(tvals, spair, offsets);
        stattn_sparse<<<dim3(Bb * (Tt / 64)), dim3(MTHREADS), 0, stream>>>(
            h_seq, spair, offsets, out);
    } else {
        stattn_naive<<<dim3(Bb * Tt), dim3(64), 0, stream>>>(h_seq, tvals, out);
    }
}

// Round 10
// 28.555 us; speedup vs baseline: 1.0273x; 1.0273x over previous
//
#include <hip/hip_runtime.h>

// SoftTimeAttention: out[b,q,:] = sum_j softmax_j(-(T*(t_q-t_j))^2) * h[b,j,:]
// B=4, T=4096, H=256, f32. w = exp(-(4096*dt)^2) == 0 in f32 for |dt|>~2.3e-3
// => ~19 active keys/query. R4-proven structure: per-batch counting sort
// (1024 buckets), then sorted-uniform query chunks per wave with a shared
// candidate window and ballot-compacted quad-row accumulation.
// R10 delta vs R4: main uses 128-thread/2-wave blocks (1024 blocks, 4/CU)
// for finest-grained load balancing; per-wave work identical to R4.

constexpr int Bb = 4;
constexpr int Tt = 4096;
constexpr int Hh = 256;
constexpr int NB = 1024;     // t-buckets per batch
// margin 2 buckets each side: dropped terms have x > 8 => w <= e^-64; with
// denominator >= 1 the output error is ~1e-26 per element: negligible.

// ---------------------------------------------------------------------------
// Per-batch counting sort (R4-proven, unchanged). One 1024-thr block per batch.
// Output: spair[b][pos] = { bitcast(t*4096), original_idx }, offsets[b][NB+1].
__global__ __launch_bounds__(1024) void sort_kernel(
    const float* __restrict__ tvals,
    uint2* __restrict__ spair,
    int* __restrict__ offsets)
{
    __shared__ int hist[NB];
    __shared__ int excl[NB];
    __shared__ int cnt[NB];
    __shared__ int wsum[16];
    __shared__ int wexcl[16];

    const int b    = blockIdx.x;
    const int tid  = threadIdx.x;
    const int lane = tid & 63;
    const int wv   = tid >> 6;
    const float* tb = tvals + (size_t)b * Tt;

    hist[tid] = 0;
    cnt[tid]  = 0;
    __syncthreads();

    float tv[4]; int bk[4];
    #pragma unroll
    for (int i = 0; i < 4; ++i) {
        const int j = i * 1024 + tid;
        const float t = tb[j];
        int k = (int)(t * (float)NB);
        k = k < 0 ? 0 : (k > NB - 1 ? NB - 1 : k);
        tv[i] = t * 4096.0f;      // pre-scaled for the main kernel
        bk[i] = k;
        atomicAdd(&hist[k], 1);
    }
    __syncthreads();

    // inclusive scan over 1024 buckets: wave scan + cross-wave fixup
    const int self = hist[tid];
    int x = self;
    #pragma unroll
    for (int d = 1; d < 64; d <<= 1) {
        const int y = __shfl_up(x, d);
        if (lane >= d) x += y;
    }
    if (lane == 63) wsum[wv] = x;
    __syncthreads();
    if (tid < 16) {
        int y = wsum[tid];
        #pragma unroll
        for (int d = 1; d < 16; d <<= 1) {
            const int z = __shfl_up(y, d);
            if (tid >= d) y += z;
        }
        wexcl[tid] = y - wsum[tid];
    }
    __syncthreads();
    const int incl = x + wexcl[wv];
    excl[tid] = incl - self;
    offsets[(size_t)b * (NB + 1) + tid] = incl - self;
    if (tid == 0) offsets[(size_t)b * (NB + 1) + NB] = Tt;
    __syncthreads();

    #pragma unroll
    for (int i = 0; i < 4; ++i) {
        const int k = bk[i];
        const int rank = atomicAdd(&cnt[k], 1);
        const int pos = excl[k] + rank;
        uint2 pr;
        pr.x = __float_as_uint(tv[i]);
        pr.y = (unsigned)(i * 1024 + tid);
        spair[(size_t)b * Tt + pos] = pr;
    }
}

// ---------------------------------------------------------------------------
// Main sparse kernel: 128 thr = 2 waves; each wave handles QPW=8 consecutive
// sorted queries (shared candidate window). Grid = B * T/16 = 1024 blocks
// -> 4 blocks/CU, fine-grained backfill; 8 waves/CU like R4.
constexpr int QPW = 8;
constexpr int MTHREADS = 128;

__global__ __launch_bounds__(MTHREADS) void stattn_sparse(
    const float* __restrict__ h_seq,
    const uint2* __restrict__ spair,
    const int* __restrict__ offsets,
    float* __restrict__ out)
{
    const int tid  = threadIdx.x;
    const int lane = tid & 63;
    const int wv   = tid >> 6;          // 0..1

    // XCD-contiguous swizzle (1024 blocks = 8 XCDs x 128): 2 XCDs per batch,
    // so the 4 MB per-batch h panel stays L2-resident.
    const int phys = blockIdx.x;
    const int lb   = (phys & 7) * 128 + (phys >> 3);
    const int b    = lb >> 8;           // 256 blocks per batch
    const int blk  = lb & 255;

    const uint2* sp  = spair + (size_t)b * Tt;
    const int*   off = offsets + (size_t)b * (NB + 1);
    const float* hb  = h_seq + (size_t)b * Tt * Hh;

    const int p0 = blk * 16 + wv * QPW;     // 16 queries per block

    float tq[QPW]; int qi[QPW];
    #pragma unroll
    for (int g = 0; g < QPW; ++g) {
        const uint2 pr = sp[p0 + g];
        tq[g] = __uint_as_float(pr.x);      // t*4096
        qi[g] = (int)pr.y;
    }

    // candidate window (buckets nondecreasing along sorted positions)
    // bucket = floor(t*1024) = floor(ts * 0.25)
    int bmin = (int)(tq[0] * 0.25f);
    int bmax = (int)(tq[QPW - 1] * 0.25f);
    bmin = bmin < 0 ? 0 : (bmin > NB - 1 ? NB - 1 : bmin);
    bmax = bmax < 0 ? 0 : (bmax > NB - 1 ? NB - 1 : bmax);
    const int blo = bmin - 2 < 0 ? 0 : bmin - 2;
    const int bhi = bmax + 3 > NB ? NB : bmax + 3;
    const int lo = off[blo];
    const int hi = off[bhi];

    float4 acc[QPW];
    float  den[QPW];
    #pragma unroll
    for (int g = 0; g < QPW; ++g) {
        acc[g] = make_float4(0.f, 0.f, 0.f, 0.f);
        den[g] = 0.f;
    }

    for (int base = lo; base < hi; base += 64) {
        const int p = base + lane;
        const bool valid = p < hi;
        float tj; int jj;
        if (valid) { const uint2 pr = sp[p]; tj = __uint_as_float(pr.x); jj = (int)pr.y; }
        else       { tj = 3.0e18f; jj = 0; }   // -> w == 0 exactly

        float w[QPW]; float wmax = 0.f;
        #pragma unroll
        for (int g = 0; g < QPW; ++g) {
            const float x = tq[g] - tj;
            w[g] = __expf(-x * x);
            den[g] += w[g];
            wmax = fmaxf(wmax, w[g]);
        }

        unsigned long long mask = __ballot(wmax > 1e-20f);
        while (mask) {
            const int s0 = __builtin_ctzll(mask); mask &= mask - 1;
            const bool h1 = mask != 0;
            const int s1 = h1 ? __builtin_ctzll(mask) : s0; if (h1) mask &= mask - 1;
            const bool h2 = mask != 0;
            const int s2 = h2 ? __builtin_ctzll(mask) : s0; if (h2) mask &= mask - 1;
            const bool h3 = mask != 0;
            const int s3 = h3 ? __builtin_ctzll(mask) : s0; if (h3) mask &= mask - 1;

            const int j0 = __shfl(jj, s0);
            const int j1 = __shfl(jj, s1);
            const int j2 = __shfl(jj, s2);
            const int j3 = __shfl(jj, s3);
            float4 h0  = *(const float4*)&hb[(size_t)j0 * Hh + lane * 4];
            float4 h1v = *(const float4*)&hb[(size_t)j1 * Hh + lane * 4];
            float4 h2v = *(const float4*)&hb[(size_t)j2 * Hh + lane * 4];
            float4 h3v = *(const float4*)&hb[(size_t)j3 * Hh + lane * 4];
            if (!h1) h1v = make_float4(0.f,0.f,0.f,0.f);
            if (!h2) h2v = make_float4(0.f,0.f,0.f,0.f);
            if (!h3) h3v = make_float4(0.f,0.f,0.f,0.f);

            #pragma unroll
            for (int g = 0; g < QPW; ++g) {
                const float a0 = __shfl(w[g], s0);
                const float a1 = __shfl(w[g], s1);
                const float a2 = __shfl(w[g], s2);
                const float a3 = __shfl(w[g], s3);
                acc[g].x += a0 * h0.x + a1 * h1v.x + a2 * h2v.x + a3 * h3v.x;
                acc[g].y += a0 * h0.y + a1 * h1v.y + a2 * h2v.y + a3 * h3v.y;
                acc[g].z += a0 * h0.z + a1 * h1v.z + a2 * h2v.z + a3 * h3v.z;
                acc[g].w += a0 * h0.w + a1 * h1v.w + a2 * h2v.w + a3 * h3v.w;
            }
        }
    }

    // reduce denominators across lanes
    #pragma unroll
    for (int g = 0; g < QPW; ++g) {
        float d = den[g];
        #pragma unroll
        for (int s = 1; s < 64; s <<= 1) d += __shfl_xor(d, s);
        den[g] = d;
    }

    #pragma unroll
    for (int g = 0; g < QPW; ++g) {
        const float inv = 1.0f / den[g];
        float* orow = out + ((size_t)b * Tt + qi[g]) * Hh + lane * 4;
        float4 o;
        o.x = acc[g].x * inv; o.y = acc[g].y * inv;
        o.z = acc[g].z * inv; o.w = acc[g].w * inv;
        *(float4*)orow = o;
    }
}

// ---------------------------------------------------------------------------
// Naive dense fallback if ws is too small (never expected; kept for safety).
__global__ __launch_bounds__(64) void stattn_naive(
    const float* __restrict__ h_seq,
    const float* __restrict__ tvals,
    float* __restrict__ out)
{
    const int gid  = blockIdx.x;        // b*Tt + q
    const int b    = gid >> 12;
    const int q    = gid & (Tt - 1);
    const int lane = threadIdx.x;
    const float* tb = tvals + (size_t)b * Tt;
    const float* hb = h_seq + (size_t)b * Tt * Hh;
    const float tsq = tb[q] * 4096.0f;
    float4 acc = make_float4(0.f,0.f,0.f,0.f);
    float den = 0.f;
    for (int j = 0; j < Tt; ++j) {
        const float x = tsq - tb[j] * 4096.0f;
        const float w = __expf(-x * x);
        den += w;
        if (w > 0.f) {
            const float4 hv = *(const float4*)&hb[(size_t)j * Hh + lane * 4];
            acc.x += w * hv.x; acc.y += w * hv.y;
            acc.z += w * hv.z; acc.w += w * hv.w;
        }
    }
    const float inv = 1.0f / den;
    float4 o;
    o.x = acc.x * inv; o.y = acc.y * inv; o.z = acc.z * inv; o.w = acc.w * inv;
    *(float4*)&out[((size_t)b * Tt + q) * Hh + lane * 4] = o;
}

extern "C" void kernel_launch(void* const* d_in, const int* in_sizes, int n_in,
                              void* d_out, int out_size, void* d_ws, size_t ws_size,
                              hipStream_t stream) {
    const float* h_seq = (const float*)d_in[0];
    const float* tvals = (const float*)d_in[1];
    float* out = (float*)d_out;

    // ws layout: spair (B*T uint2) | offsets (B*(NB+1) i32)
    const size_t need = (size_t)Bb * Tt * sizeof(uint2) + (size_t)Bb * (NB + 1) * 4;
    if (ws_size >= need) {
        uint2* spair   = (uint2*)d_ws;
        int*   offsets = (int*)(spair + (size_t)Bb * Tt);
        sort_kernel<<<dim3(Bb), dim3(1024), 0, stream>>>(tvals, spair, offsets);
        stattn_sparse<<<dim3(Bb * (Tt / 16)), dim3(MTHREADS), 0, stream>>>(
            h_seq, spair, offsets, out);
    } else {
        stattn_naive<<<dim3(Bb * Tt), dim3(64), 0, stream>>>(h_seq, tvals, out);
    }
}

// Round 11
// 22.407 us; speedup vs baseline: 1.3091x; 1.2743x over previous
//
#include <hip/hip_runtime.h>
#include <hip/hip_bf16.h>

// SoftTimeAttention: out[b,q,:] = sum_j softmax_j(-(T*(t_q-t_j))^2) * h[b,j,:]
// B=4, T=4096, H=256, f32. w = exp(-(4096*dt)^2) == 0 in f32 for |dt| > ~2.3e-3
// => ~19 active keys per query. Bucket-sort t (1024 buckets), process queries in
// sorted order; each wave shares one candidate window across QPW queries.
//
// R11 = byte-identical replication of the round-4 kernel (22.9 us) as a
// session-variance control: R5-R10 structural variants all landed 28.5-32.1
// regardless of design; this run decides regime vs structure.

constexpr int Bb = 4;
constexpr int Tt = 4096;
constexpr int Hh = 256;
constexpr int NB = 1024;     // t-buckets per batch
// coverage: |dt| <= 2/1024 <=> w >= exp(-64); buckets [k-2, k+2] suffice.

// ---------------------------------------------------------------------------
// Per-batch counting sort. One block (1024 thr) per batch.
// Output: spair[b][pos] = { bitcast(t*4096), original_idx }, offsets[b][NB+1].
__global__ __launch_bounds__(1024) void sort_kernel(
    const float* __restrict__ tvals,
    uint2* __restrict__ spair,
    int* __restrict__ offsets)
{
    __shared__ int hist[NB];
    __shared__ int excl[NB];
    __shared__ int cnt[NB];
    __shared__ int wsum[16];
    __shared__ int wexcl[16];

    const int b    = blockIdx.x;
    const int tid  = threadIdx.x;
    const int lane = tid & 63;
    const int wv   = tid >> 6;
    const float* tb = tvals + (size_t)b * Tt;

    hist[tid] = 0;
    cnt[tid]  = 0;
    __syncthreads();

    float tv[4]; int bk[4];
    #pragma unroll
    for (int i = 0; i < 4; ++i) {
        const int j = i * 1024 + tid;
        const float t = tb[j];
        int k = (int)(t * (float)NB);
        k = k < 0 ? 0 : (k > NB - 1 ? NB - 1 : k);
        tv[i] = t * 4096.0f;      // pre-scaled for the main kernel
        bk[i] = k;
        atomicAdd(&hist[k], 1);
    }
    __syncthreads();

    // inclusive scan over 1024 buckets: wave scan + cross-wave fixup
    const int self = hist[tid];
    int x = self;
    #pragma unroll
    for (int d = 1; d < 64; d <<= 1) {
        const int y = __shfl_up(x, d);
        if (lane >= d) x += y;
    }
    if (lane == 63) wsum[wv] = x;
    __syncthreads();
    if (tid < 16) {
        int y = wsum[tid];
        #pragma unroll
        for (int d = 1; d < 16; d <<= 1) {
            const int z = __shfl_up(y, d);
            if (tid >= d) y += z;
        }
        wexcl[tid] = y - wsum[tid];
    }
    __syncthreads();
    const int incl = x + wexcl[wv];
    excl[tid] = incl - self;
    offsets[(size_t)b * (NB + 1) + tid] = incl - self;
    if (tid == 0) offsets[(size_t)b * (NB + 1) + NB] = Tt;
    __syncthreads();

    #pragma unroll
    for (int i = 0; i < 4; ++i) {
        const int k = bk[i];
        const int rank = atomicAdd(&cnt[k], 1);
        const int pos = excl[k] + rank;
        uint2 pr;
        pr.x = __float_as_uint(tv[i]);
        pr.y = (unsigned)(i * 1024 + tid);
        spair[(size_t)b * Tt + pos] = pr;
    }
}

// ---------------------------------------------------------------------------
// Main sparse kernel: 256 thr = 4 waves; each wave handles QPW=8 consecutive
// sorted queries (shared candidate window). Grid = B * T/32 = 512 blocks.
constexpr int QPW = 8;
constexpr int MTHREADS = 256;

__global__ __launch_bounds__(MTHREADS) void stattn_sparse(
    const float* __restrict__ h_seq,
    const uint2* __restrict__ spair,
    const int* __restrict__ offsets,
    float* __restrict__ out)
{
    const int tid  = threadIdx.x;
    const int lane = tid & 63;
    const int wv   = tid >> 6;

    // XCD-contiguous swizzle (512 blocks = 8 XCDs x 64): 2 XCDs per batch.
    const int phys = blockIdx.x;
    const int lb   = (phys & 7) * 64 + (phys >> 3);
    const int b    = lb >> 7;
    const int blk  = lb & 127;

    const uint2* sp  = spair + (size_t)b * Tt;
    const int*   off = offsets + (size_t)b * (NB + 1);
    const float* hb  = h_seq + (size_t)b * Tt * Hh;

    const int p0 = blk * 32 + wv * QPW;

    float tq[QPW]; int qi[QPW];
    #pragma unroll
    for (int g = 0; g < QPW; ++g) {
        const uint2 pr = sp[p0 + g];
        tq[g] = __uint_as_float(pr.x);     // t*4096
        qi[g] = (int)pr.y;
    }

    // candidate window (buckets nondecreasing along sorted positions)
    // bucket = floor(t*1024) = floor(ts * 0.25)
    int bmin = (int)(tq[0] * 0.25f);
    int bmax = (int)(tq[QPW - 1] * 0.25f);
    bmin = bmin < 0 ? 0 : (bmin > NB - 1 ? NB - 1 : bmin);
    bmax = bmax < 0 ? 0 : (bmax > NB - 1 ? NB - 1 : bmax);
    const int blo = bmin - 2 < 0 ? 0 : bmin - 2;
    const int bhi = bmax + 3 > NB ? NB : bmax + 3;
    const int lo = off[blo];
    const int hi = off[bhi];

    float4 acc[QPW];
    float  den[QPW];
    #pragma unroll
    for (int g = 0; g < QPW; ++g) {
        acc[g] = make_float4(0.f, 0.f, 0.f, 0.f);
        den[g] = 0.f;
    }

    for (int base = lo; base < hi; base += 64) {
        const int p = base + lane;
        const bool valid = p < hi;
        float tj; int jj;
        if (valid) { const uint2 pr = sp[p]; tj = __uint_as_float(pr.x); jj = (int)pr.y; }
        else       { tj = 3.0e18f; jj = 0; }   // -> w == 0 exactly

        float w[QPW]; float wmax = 0.f;
        #pragma unroll
        for (int g = 0; g < QPW; ++g) {
            const float x = tq[g] - tj;
            w[g] = __expf(-x * x);
            den[g] += w[g];
            wmax = fmaxf(wmax, w[g]);
        }

        unsigned long long mask = __ballot(wmax > 1e-20f);
        while (mask) {
            const int s0 = __builtin_ctzll(mask); mask &= mask - 1;
            const bool h1 = mask != 0;
            const int s1 = h1 ? __builtin_ctzll(mask) : s0; if (h1) mask &= mask - 1;
            const bool h2 = mask != 0;
            const int s2 = h2 ? __builtin_ctzll(mask) : s0; if (h2) mask &= mask - 1;
            const bool h3 = mask != 0;
            const int s3 = h3 ? __builtin_ctzll(mask) : s0; if (h3) mask &= mask - 1;

            const int j0 = __shfl(jj, s0);
            const int j1 = __shfl(jj, s1);
            const int j2 = __shfl(jj, s2);
            const int j3 = __shfl(jj, s3);
            float4 h0 = *(const float4*)&hb[(size_t)j0 * Hh + lane * 4];
            float4 h1v = *(const float4*)&hb[(size_t)j1 * Hh + lane * 4];
            float4 h2v = *(const float4*)&hb[(size_t)j2 * Hh + lane * 4];
            float4 h3v = *(const float4*)&hb[(size_t)j3 * Hh + lane * 4];
            // mask out duplicated slots once (amortized over all QPW queries)
            if (!h1) { h1v.x = 0.f; h1v.y = 0.f; h1v.z = 0.f; h1v.w = 0.f; }
            if (!h2) { h2v.x = 0.f; h2v.y = 0.f; h2v.z = 0.f; h2v.w = 0.f; }
            if (!h3) { h3v.x = 0.f; h3v.y = 0.f; h3v.z = 0.f; h3v.w = 0.f; }

            #pragma unroll
            for (int g = 0; g < QPW; ++g) {
                const float a0 = __shfl(w[g], s0);
                const float a1 = __shfl(w[g], s1);
                const float a2 = __shfl(w[g], s2);
                const float a3 = __shfl(w[g], s3);
                acc[g].x += a0 * h0.x; acc[g].y += a0 * h0.y;
                acc[g].z += a0 * h0.z; acc[g].w += a0 * h0.w;
                acc[g].x += a1 * h1v.x; acc[g].y += a1 * h1v.y;
                acc[g].z += a1 * h1v.z; acc[g].w += a1 * h1v.w;
                acc[g].x += a2 * h2v.x; acc[g].y += a2 * h2v.y;
                acc[g].z += a2 * h2v.z; acc[g].w += a2 * h2v.w;
                acc[g].x += a3 * h3v.x; acc[g].y += a3 * h3v.y;
                acc[g].z += a3 * h3v.z; acc[g].w += a3 * h3v.w;
            }
        }
    }

    // reduce denominators across lanes
    #pragma unroll
    for (int g = 0; g < QPW; ++g) {
        float d = den[g];
        #pragma unroll
        for (int s = 1; s < 64; s <<= 1) d += __shfl_xor(d, s);
        den[g] = d;
    }

    #pragma unroll
    for (int g = 0; g < QPW; ++g) {
        const float inv = 1.0f / den[g];
        float* orow = out + ((size_t)b * Tt + qi[g]) * Hh + lane * 4;
        float4 o;
        o.x = acc[g].x * inv; o.y = acc[g].y * inv;
        o.z = acc[g].z * inv; o.w = acc[g].w * inv;
        *(float4*)orow = o;
    }
}

// ---------------------------------------------------------------------------
// Fallback dense f32 kernel (round-1 proven) if ws is too small.
constexpr int QB = 64;
constexpr int JB = 64;
constexpr int NT = Tt / JB;
constexpr int NTHREADS = 512;

__device__ __forceinline__ void gld16(const void* g, void* l) {
    __builtin_amdgcn_global_load_lds(
        (const __attribute__((address_space(1))) void*)g,
        (__attribute__((address_space(3))) void*)l, 16, 0, 0);
}
__device__ __forceinline__ void gld4(const void* g, void* l) {
    __builtin_amdgcn_global_load_lds(
        (const __attribute__((address_space(1))) void*)g,
        (__attribute__((address_space(3))) void*)l, 4, 0, 0);
}

__global__ __launch_bounds__(NTHREADS, 2) void stattn_kernel(
    const float* __restrict__ h_seq,
    const float* __restrict__ tvals,
    float* __restrict__ out)
{
    __shared__ float hbuf[2][JB][Hh];
    __shared__ float wbuf[JB][QB];
    __shared__ float tjbuf[2][JB];
    __shared__ float sden[QB];
    __shared__ float tqs[QB];

    const int tid  = threadIdx.x;
    const int lane = tid & 63;
    const int wv   = tid >> 6;
    const int phys = blockIdx.x;
    const int lb   = (phys & 7) * 32 + (phys >> 3);
    const int b    = lb >> 6;
    const int qt   = lb & 63;
    const int q0   = qt * QB;

    const float* hb = h_seq + (size_t)b * Tt * Hh;
    const float* tb = tvals + (size_t)b * Tt;

    if (tid < QB) { tqs[tid] = tb[q0 + tid]; sden[tid] = 0.0f; }

    float acc[8][4];
    #pragma unroll
    for (int k = 0; k < 8; ++k)
        #pragma unroll
        for (int c = 0; c < 4; ++c) acc[k][c] = 0.0f;

    const float Tf = (float)Tt;

    auto stage = [&](int buf, int tile) {
        const float* src = hb + (size_t)tile * JB * Hh;
        float* dst = &hbuf[buf][0][0];
        #pragma unroll
        for (int i = 0; i < 8; ++i) {
            const int off = i * (NTHREADS * 4) + tid * 4;
            gld16(src + off, dst + off);
        }
        gld4(tb + tile * JB + lane, &tjbuf[buf][lane]);
    };

    stage(0, 0);
    __syncthreads();

    const int qw = wv * 8;

    for (int t = 0; t < NT; ++t) {
        const int cur = t & 1;
        __syncthreads();
        {
            const int q  = tid & 63;
            const int jg = tid >> 6;
            const float tqv = tqs[q];
            const float4 tj0 = *(const float4*)&tjbuf[cur][jg * 8];
            const float4 tj1 = *(const float4*)&tjbuf[cur][jg * 8 + 4];
            const float tjv[8] = {tj0.x, tj0.y, tj0.z, tj0.w,
                                  tj1.x, tj1.y, tj1.z, tj1.w};
            float part = 0.0f;
            #pragma unroll
            for (int jj = 0; jj < 8; ++jj) {
                const float d = Tf * (tqv - tjv[jj]);
                const float w = __expf(-d * d);
                wbuf[jg * 8 + jj][q] = w;
                part += w;
            }
            atomicAdd(&sden[q], part);
        }
        if (t + 1 < NT) stage((t + 1) & 1, t + 1);
        asm volatile("s_waitcnt lgkmcnt(0)" ::: "memory");
        __builtin_amdgcn_s_barrier();
        asm volatile("" ::: "memory");
        #pragma unroll 2
        for (int j = 0; j < JB; ++j) {
            const float4 hv = *(const float4*)&hbuf[cur][j][lane * 4];
            const float4 w0 = *(const float4*)&wbuf[j][qw];
            const float4 w1 = *(const float4*)&wbuf[j][qw + 4];
            const float wr[8] = {w0.x, w0.y, w0.z, w0.w,
                                 w1.x, w1.y, w1.z, w1.w};
            #pragma unroll
            for (int k = 0; k < 8; ++k) {
                acc[k][0] += wr[k] * hv.x;
                acc[k][1] += wr[k] * hv.y;
                acc[k][2] += wr[k] * hv.z;
                acc[k][3] += wr[k] * hv.w;
            }
        }
    }

    #pragma unroll
    for (int k = 0; k < 8; ++k) {
        const int q = q0 + qw + k;
        const float inv = 1.0f / sden[qw + k];
        float4 o;
        o.x = acc[k][0] * inv;
        o.y = acc[k][1] * inv;
        o.z = acc[k][2] * inv;
        o.w = acc[k][3] * inv;
        *(float4*)&out[((size_t)b * Tt + q) * Hh + (size_t)(lane * 4)] = o;
    }
}

extern "C" void kernel_launch(void* const* d_in, const int* in_sizes, int n_in,
                              void* d_out, int out_size, void* d_ws, size_t ws_size,
                              hipStream_t stream) {
    const float* h_seq = (const float*)d_in[0];
    const float* tvals = (const float*)d_in[1];
    float* out = (float*)d_out;

    // ws layout: spair (B*T uint2) | offsets (B*(NB+1) i32)
    const size_t need = (size_t)Bb * Tt * sizeof(uint2) + (size_t)Bb * (NB + 1) * 4;
    if (ws_size >= need) {
        uint2* spair  = (uint2*)d_ws;
        int*   offsets = (int*)(spair + (size_t)Bb * Tt);
        sort_kernel<<<dim3(Bb), dim3(1024), 0, stream>>>(tvals, spair, offsets);
        stattn_sparse<<<dim3(Bb * (Tt / 32)), dim3(MTHREADS), 0, stream>>>(
            h_seq, spair, offsets, out);
    } else {
        stattn_kernel<<<dim3(Bb * (Tt / QB)), dim3(NTHREADS), 0, stream>>>(
            h_seq, tvals, out);
    }
}